// Round 7
// baseline (49.789 us; speedup 1.0000x reference)
//
#include <hip/hip_runtime.h>

#define NROWS 4096
#define DDIM  256
#define BDIM  16
#define RBLKS 256                 // 16 rows per row-block
#define BSETS 4                   // 4 instances per block
#define NB1   (RBLKS * BSETS)     // 1024 blocks
#define GRPSZ 16                  // completion-tree fan-in
#define NGRP  (NB1 / GRPSZ)       // 64 group counters
#define CNT_BASE 16384            // byte offset of counters in ws
#define CNT_STRIDE 32             // uints between group counters (128 B)

// Fused kernel, no fences. Block = rblk*4 + bset (rblk fast -> stratified rows
// per CU). Wave: 4 groups of 16 lanes, group g owns row n; lane j covers cols
// {4j+64m}. Cross-block handoff entirely via agent-scope atomics (write-through
// to the coherence point) -> release ordering is just a vmcnt wait, no L2
// writeback (the R5 123us disaster was per-block __threadfence).
__global__ __launch_bounds__(256) void cos_fused_kernel(
    const float* __restrict__ stat, const float* __restrict__ con,
    const int* __restrict__ lens, float* __restrict__ partial,
    unsigned int* __restrict__ cnts, float* __restrict__ out) {
  const int rblk = blockIdx.x >> 2;          // 0..255
  const int bset = blockIdx.x & (BSETS - 1); // 0..3
  const int wave = threadIdx.x >> 6;
  const int lane = threadIdx.x & 63;
  const int g    = lane >> 4;
  const int j    = lane & 15;
  const int n    = rblk * 16 + wave * 4 + g; // this lane's row
  const int b0   = bset * 4;

  float acc[4];
  #pragma unroll
  for (int bi = 0; bi < 4; ++bi) {
    const int b      = b0 + bi;
    const int len    = lens[b];
    const bool valid = (n < len);

    float dot = 0.0f, ns = 0.0f, nc = 0.0f;
    if (valid) {  // group-uniform branch; invalid rows cost no traffic
      const size_t base = (size_t)b * (NROWS * DDIM) + (size_t)n * DDIM + (j << 2);
      const float* pa = stat + base;
      const float* pc = con + base;
      #pragma unroll
      for (int m = 0; m < 4; ++m) {
        const float4 a = *reinterpret_cast<const float4*>(pa + (m << 6));
        const float4 c = *reinterpret_cast<const float4*>(pc + (m << 6));
        dot = fmaf(a.x, c.x, fmaf(a.y, c.y, fmaf(a.z, c.z, fmaf(a.w, c.w, dot))));
        ns  = fmaf(a.x, a.x, fmaf(a.y, a.y, fmaf(a.z, a.z, fmaf(a.w, a.w, ns))));
        nc  = fmaf(c.x, c.x, fmaf(c.y, c.y, fmaf(c.z, c.z, fmaf(c.w, c.w, nc))));
      }
    }
    #pragma unroll
    for (int off = 1; off < 16; off <<= 1) {   // 4-stage, within 16-lane group
      dot += __shfl_xor(dot, off);
      ns  += __shfl_xor(ns,  off);
      nc  += __shfl_xor(nc,  off);
    }
    float cosv = valid ? dot * rsqrtf(ns) * rsqrtf(nc) : 0.0f; // eps unreachable
    cosv += __shfl_xor(cosv, 16);              // sum the wave's 4 rows
    cosv += __shfl_xor(cosv, 32);
    acc[bi] = cosv;
  }

  __shared__ float sh[4][4];
  __shared__ int   is_last;
  if (lane == 0) {
    #pragma unroll
    for (int bi = 0; bi < 4; ++bi) sh[wave][bi] = acc[bi];
  }
  __syncthreads();

  if (threadIdx.x == 0) {
    #pragma unroll
    for (int bi = 0; bi < 4; ++bi) {
      const float v = sh[0][bi] + sh[1][bi] + sh[2][bi] + sh[3][bi];
      // write-through atomic store: visible at coherence point, no dirty L2
      __hip_atomic_store(&partial[(b0 + bi) * RBLKS + rblk], v,
                         __ATOMIC_RELAXED, __HIP_MEMORY_SCOPE_AGENT);
    }
    int last = 0;
    const int grp = blockIdx.x >> 4;  // 16 consecutive blocks per group
    // RELEASE add = vmcnt-wait + atomic; no cache invalidate storm
    const unsigned p = __hip_atomic_fetch_add(&cnts[grp * CNT_STRIDE], 1u,
                          __ATOMIC_RELEASE, __HIP_MEMORY_SCOPE_AGENT);
    if (p == GRPSZ - 1) {
      const unsigned q = __hip_atomic_fetch_add(&cnts[NGRP * CNT_STRIDE], 1u,
                            __ATOMIC_RELEASE, __HIP_MEMORY_SCOPE_AGENT);
      if (q == NGRP - 1) last = 1;
    }
    is_last = last;
  }
  __syncthreads();

  if (is_last) {
    if (threadIdx.x == 0) {
      (void)__hip_atomic_load(&cnts[NGRP * CNT_STRIDE], __ATOMIC_ACQUIRE,
                              __HIP_MEMORY_SCOPE_AGENT);
    }
    __syncthreads();
    __shared__ float shl[BDIM];
    #pragma unroll
    for (int bi = 0; bi < 4; ++bi) {
      const int b = wave * 4 + bi;
      float v = 0.0f;
      #pragma unroll
      for (int m = 0; m < RBLKS / 64; ++m)
        v += __hip_atomic_load(&partial[b * RBLKS + (m << 6) + lane],
                               __ATOMIC_RELAXED, __HIP_MEMORY_SCOPE_AGENT);
      #pragma unroll
      for (int off = 1; off < 64; off <<= 1) v += __shfl_xor(v, off);
      if (lane == 0) {
        const int len = lens[b];
        shl[b] = (len > 0) ? (1.0f - v / (float)len) : 0.0f;
      }
    }
    __syncthreads();
    if (threadIdx.x == 0) {
      float t = 0.0f;
      #pragma unroll
      for (int i = 0; i < BDIM; ++i) t += shl[i];
      out[0] = t * (1.0f / BDIM);
    }
  }
}

extern "C" void kernel_launch(void* const* d_in, const int* in_sizes, int n_in,
                              void* d_out, int out_size, void* d_ws, size_t ws_size,
                              hipStream_t stream) {
  const float* stat = (const float*)d_in[0];
  const float* con  = (const float*)d_in[1];
  const int*   lens = (const int*)d_in[2];
  float*       out  = (float*)d_out;
  float*       partial = (float*)d_ws;                                // 16 KB
  unsigned int* cnts = (unsigned int*)((char*)d_ws + CNT_BASE);

  // zero the 64 group counters + top counter (graph-capturable)
  hipMemsetAsync(cnts, 0, (NGRP * CNT_STRIDE + CNT_STRIDE) * sizeof(unsigned int),
                 stream);

  dim3 grid(NB1);
  dim3 blk(256);
  hipLaunchKernelGGL(cos_fused_kernel, grid, blk, 0, stream,
                     stat, con, lens, partial, cnts, out);
}

// Round 8
// 25.239 us; speedup vs baseline: 1.9727x; 1.9727x over previous
//
#include <hip/hip_runtime.h>

#define NROWS 4096
#define DDIM  256
#define BDIM  16
#define RBLKS 256                 // 16 rows per row-block
#define BSETS 4                   // 4 instances per block
#define NB1   (RBLKS * BSETS)     // 1024 blocks
#define GRPSZ 16                  // completion-tree fan-in
#define NGRP  (NB1 / GRPSZ)       // 64 group counters
#define CNT_BASE 16384            // byte offset of counters in ws
#define CNT_STRIDE 32             // uints between group counters (128 B)

// Fused kernel with ZERO release/fence operations (R5/R7 lesson: each per-block
// release/threadfence costs ~50-60ns serialized chip-wide = tens of us at this
// grid). Ordering is done AITER-style with raw vmcnt waits:
//   relaxed agent store (write-through, acked at coherence point)
//   -> s_waitcnt vmcnt(0)                      [ack = globally visible]
//   -> relaxed counter add (tree, return value branches force completion)
//   -> elected last block reads partials with relaxed agent loads.
__global__ __launch_bounds__(256) void cos_fused_kernel(
    const float* __restrict__ stat, const float* __restrict__ con,
    const int* __restrict__ lens, float* __restrict__ partial,
    unsigned int* __restrict__ cnts, float* __restrict__ out) {
  const int rblk = blockIdx.x >> 2;          // 0..255 (rblk fast -> stratified rows/CU)
  const int bset = blockIdx.x & (BSETS - 1); // 0..3
  const int wave = threadIdx.x >> 6;
  const int lane = threadIdx.x & 63;
  const int g    = lane >> 4;
  const int j    = lane & 15;
  const int n    = rblk * 16 + wave * 4 + g; // this lane's row
  const int b0   = bset * 4;

  float acc[4];
  #pragma unroll
  for (int bi = 0; bi < 4; ++bi) {
    const int b      = b0 + bi;
    const int len    = lens[b];
    const bool valid = (n < len);

    float dot = 0.0f, ns = 0.0f, nc = 0.0f;
    if (valid) {  // group-uniform branch; invalid rows cost no traffic
      const size_t base = (size_t)b * (NROWS * DDIM) + (size_t)n * DDIM + (j << 2);
      const float* pa = stat + base;
      const float* pc = con + base;
      #pragma unroll
      for (int m = 0; m < 4; ++m) {
        const float4 a = *reinterpret_cast<const float4*>(pa + (m << 6));
        const float4 c = *reinterpret_cast<const float4*>(pc + (m << 6));
        dot = fmaf(a.x, c.x, fmaf(a.y, c.y, fmaf(a.z, c.z, fmaf(a.w, c.w, dot))));
        ns  = fmaf(a.x, a.x, fmaf(a.y, a.y, fmaf(a.z, a.z, fmaf(a.w, a.w, ns))));
        nc  = fmaf(c.x, c.x, fmaf(c.y, c.y, fmaf(c.z, c.z, fmaf(c.w, c.w, nc))));
      }
    }
    #pragma unroll
    for (int off = 1; off < 16; off <<= 1) {   // 4-stage, within 16-lane group
      dot += __shfl_xor(dot, off);
      ns  += __shfl_xor(ns,  off);
      nc  += __shfl_xor(nc,  off);
    }
    float cosv = valid ? dot * rsqrtf(ns) * rsqrtf(nc) : 0.0f; // eps unreachable
    cosv += __shfl_xor(cosv, 16);              // sum the wave's 4 rows
    cosv += __shfl_xor(cosv, 32);
    acc[bi] = cosv;
  }

  __shared__ float sh[4][4];
  __shared__ int   is_last;
  if (lane == 0) {
    #pragma unroll
    for (int bi = 0; bi < 4; ++bi) sh[wave][bi] = acc[bi];
  }
  __syncthreads();

  if (threadIdx.x == 0) {
    #pragma unroll
    for (int bi = 0; bi < 4; ++bi) {
      const float v = sh[0][bi] + sh[1][bi] + sh[2][bi] + sh[3][bi];
      // relaxed write-through store: no cache maintenance, acked at coherence pt
      __hip_atomic_store(&partial[(b0 + bi) * RBLKS + rblk], v,
                         __ATOMIC_RELAXED, __HIP_MEMORY_SCOPE_AGENT);
    }
    // wait for the 4 stores' acks -> globally visible; costs only the drain
    asm volatile("s_waitcnt vmcnt(0)" ::: "memory");
    int last = 0;
    const int grp = blockIdx.x >> 4;  // 16 consecutive blocks per group
    const unsigned p = __hip_atomic_fetch_add(&cnts[grp * CNT_STRIDE], 1u,
                          __ATOMIC_RELAXED, __HIP_MEMORY_SCOPE_AGENT);
    if (p == GRPSZ - 1) {             // branch on p forces completion before next add
      const unsigned q = __hip_atomic_fetch_add(&cnts[NGRP * CNT_STRIDE], 1u,
                            __ATOMIC_RELAXED, __HIP_MEMORY_SCOPE_AGENT);
      if (q == NGRP - 1) last = 1;
    }
    is_last = last;
  }
  __syncthreads();

  if (is_last) {
    asm volatile("s_waitcnt vmcnt(0)" ::: "memory");  // compiler barrier, free
    __shared__ float shl[BDIM];
    #pragma unroll
    for (int bi = 0; bi < 4; ++bi) {
      const int b = wave * 4 + bi;
      float v = 0.0f;
      #pragma unroll
      for (int m = 0; m < RBLKS / 64; ++m)
        v += __hip_atomic_load(&partial[b * RBLKS + (m << 6) + lane],
                               __ATOMIC_RELAXED, __HIP_MEMORY_SCOPE_AGENT);
      #pragma unroll
      for (int off = 1; off < 64; off <<= 1) v += __shfl_xor(v, off);
      if (lane == 0) {
        const int len = lens[b];
        shl[b] = (len > 0) ? (1.0f - v / (float)len) : 0.0f;
      }
    }
    __syncthreads();
    if (threadIdx.x == 0) {
      float t = 0.0f;
      #pragma unroll
      for (int i = 0; i < BDIM; ++i) t += shl[i];
      out[0] = t * (1.0f / BDIM);
    }
  }
}

extern "C" void kernel_launch(void* const* d_in, const int* in_sizes, int n_in,
                              void* d_out, int out_size, void* d_ws, size_t ws_size,
                              hipStream_t stream) {
  const float* stat = (const float*)d_in[0];
  const float* con  = (const float*)d_in[1];
  const int*   lens = (const int*)d_in[2];
  float*       out  = (float*)d_out;
  float*       partial = (float*)d_ws;                                // 16 KB
  unsigned int* cnts = (unsigned int*)((char*)d_ws + CNT_BASE);

  // zero the 64 group counters + top counter (graph-capturable)
  hipMemsetAsync(cnts, 0, (NGRP * CNT_STRIDE + CNT_STRIDE) * sizeof(unsigned int),
                 stream);

  dim3 grid(NB1);
  dim3 blk(256);
  hipLaunchKernelGGL(cos_fused_kernel, grid, blk, 0, stream,
                     stat, con, lens, partial, cnts, out);
}

// Round 9
// 21.163 us; speedup vs baseline: 2.3526x; 1.1926x over previous
//
#include <hip/hip_runtime.h>

#define NROWS 4096
#define DDIM  256
#define BDIM  16
#define RBLKS 256           // row-blocks, 16 rows each
#define BSETS 8             // instance-pairs; 2 instances per block
#define NB1   (RBLKS * BSETS)  // 2048 blocks -> 8 blocks/CU, 32 waves/CU

// Kernel 1. Block i decodes: rblk = i>>3, bset = ((i&7) + (i>>8)) & 7.
// Resident blocks on CU c are {c+256k, k=0..7}: bset = (c&7+k)&7 covers ALL
// 8 bsets (16 instances), rblk = c/8+32k is row-stratified -> per-CU work
// balanced to a few % for any length distribution. (R6's bset=i&3 pinned one
// bset per CU -> ~30% imbalance; R4 pinned one rblk -> ~2x.)
// Wave layout: 4 groups of 16 lanes; group g owns row n; lane j covers cols
// {4j+64m : m=0..3} (256 B contiguous per group per load -> coalesced).
__global__ __launch_bounds__(256) void cos_partial_kernel(
    const float* __restrict__ stat, const float* __restrict__ con,
    const int* __restrict__ lens, float* __restrict__ ws) {
  const int i    = blockIdx.x;
  const int rblk = i >> 3;                     // 0..255
  const int bset = ((i & 7) + (i >> 8)) & 7;   // 0..7
  const int wave = threadIdx.x >> 6;
  const int lane = threadIdx.x & 63;
  const int g    = lane >> 4;
  const int j    = lane & 15;

  const int n  = rblk * 16 + wave * 4 + g;     // this lane's row
  const int b0 = bset * 2;

  float acc[2];

  #pragma unroll
  for (int bi = 0; bi < 2; ++bi) {
    const int b      = b0 + bi;
    const int len    = lens[b];
    const bool valid = (n < len);

    float dot = 0.0f, ns = 0.0f, nc = 0.0f;
    if (valid) {  // group-uniform branch; invalid rows cost no traffic
      const size_t base = (size_t)b * (NROWS * DDIM) + (size_t)n * DDIM + (j << 2);
      const float* pa = stat + base;
      const float* pc = con + base;
      #pragma unroll
      for (int m = 0; m < 4; ++m) {
        const float4 a = *reinterpret_cast<const float4*>(pa + (m << 6));
        const float4 c = *reinterpret_cast<const float4*>(pc + (m << 6));
        dot = fmaf(a.x, c.x, fmaf(a.y, c.y, fmaf(a.z, c.z, fmaf(a.w, c.w, dot))));
        ns  = fmaf(a.x, a.x, fmaf(a.y, a.y, fmaf(a.z, a.z, fmaf(a.w, a.w, ns))));
        nc  = fmaf(c.x, c.x, fmaf(c.y, c.y, fmaf(c.z, c.z, fmaf(c.w, c.w, nc))));
      }
    }
    // 4-stage butterfly within each 16-lane group
    #pragma unroll
    for (int off = 1; off < 16; off <<= 1) {
      dot += __shfl_xor(dot, off);
      ns  += __shfl_xor(ns,  off);
      nc  += __shfl_xor(nc,  off);
    }
    float cosv = valid ? dot * rsqrtf(ns) * rsqrtf(nc) : 0.0f; // eps unreachable
    cosv += __shfl_xor(cosv, 16);   // sum the wave's 4 row-groups
    cosv += __shfl_xor(cosv, 32);
    acc[bi] = cosv;
  }

  __shared__ float sh[4][2];
  if (lane == 0) {
    #pragma unroll
    for (int bi = 0; bi < 2; ++bi) sh[wave][bi] = acc[bi];
  }
  __syncthreads();
  if (threadIdx.x < 2) {
    const int b = b0 + threadIdx.x;
    ws[b * RBLKS + rblk] =
        sh[0][threadIdx.x] + sh[1][threadIdx.x] + sh[2][threadIdx.x] + sh[3][threadIdx.x];
  }
}

// Kernel 2: one block, 256 threads. Wave w reduces instances 4w..4w+3
// (coalesced reads of 256 partials each), thread 0 combines sequentially.
__global__ __launch_bounds__(256) void cos_final_kernel(
    const float* __restrict__ ws, const int* __restrict__ lens,
    float* __restrict__ out, int B) {
  const int wave = threadIdx.x >> 6;
  const int lane = threadIdx.x & 63;

  __shared__ float shl[BDIM];

  #pragma unroll
  for (int bi = 0; bi < 4; ++bi) {
    const int b = wave * 4 + bi;
    float v = 0.0f;
    #pragma unroll
    for (int m = 0; m < RBLKS / 64; ++m) v += ws[b * RBLKS + (m << 6) + lane];
    #pragma unroll
    for (int off = 1; off < 64; off <<= 1) v += __shfl_xor(v, off);
    if (lane == 0) {
      const int len = lens[b];
      shl[b] = (len > 0) ? (1.0f - v / (float)len) : 0.0f;
    }
  }
  __syncthreads();
  if (threadIdx.x == 0) {
    float t = 0.0f;
    #pragma unroll
    for (int i = 0; i < BDIM; ++i) t += shl[i];
    out[0] = t * (1.0f / BDIM);
  }
}

extern "C" void kernel_launch(void* const* d_in, const int* in_sizes, int n_in,
                              void* d_out, int out_size, void* d_ws, size_t ws_size,
                              hipStream_t stream) {
  const float* stat = (const float*)d_in[0];
  const float* con  = (const float*)d_in[1];
  const int*   lens = (const int*)d_in[2];
  float*       out  = (float*)d_out;
  float*       ws   = (float*)d_ws;

  const int B = in_sizes[2];           // 16

  dim3 grid1(NB1);
  dim3 blk1(256);
  hipLaunchKernelGGL(cos_partial_kernel, grid1, blk1, 0, stream, stat, con, lens, ws);

  dim3 grid2(1);
  dim3 blk2(256);
  hipLaunchKernelGGL(cos_final_kernel, grid2, blk2, 0, stream, ws, lens, out, B);
}